// Round 1
// 819.819 us; speedup vs baseline: 1.0470x; 1.0470x over previous
//
#include <hip/hip_runtime.h>
#include <stdint.h>

// Problem constants (B*L=8192 tokens, D=1024, H=2048, E=8 top-2, S=1 shared)
#define T_TOK 8192
#define DIMV  1024
#define HIDV  2048
#define NE    8
#define CAP   8192          // per-expert token list capacity (2^13)
#define ROUTED 16384        // total routed assignments
#define ASSIGN_TOT 24576    // routed + 8192 shared rows
#define NCAT  4096          // interleaved up-proj N: w1|w3 in 16-col groups

typedef __attribute__((ext_vector_type(8))) short          bf16x8;
typedef __attribute__((ext_vector_type(8))) unsigned short u16x8;
typedef __attribute__((ext_vector_type(4))) float          floatx4;

__device__ __forceinline__ unsigned short f2bf(float f) {
    union { float f; unsigned int i; } v; v.f = f;
    unsigned int i = v.i;
    return (unsigned short)((i + 0x7FFFu + ((i >> 16) & 1u)) >> 16);   // RNE
}
__device__ __forceinline__ float bf2f(unsigned short u) {
    union { unsigned int i; float f; } v; v.i = ((unsigned int)u) << 16; return v.f;
}

// async global->LDS, 16B/lane; lds base wave-uniform (HW adds lane*16)
__device__ __forceinline__ void gll16(const void* g, void* l) {
    __builtin_amdgcn_global_load_lds((const __attribute__((address_space(1))) void*)g,
                                     (__attribute__((address_space(3))) void*)l,
                                     16, 0, 0);
}

// ---------------------------------------------------------------- router
// one wave per token: fp32 logits, top-2 (lowest-index tie-break), softmax.
__global__ __launch_bounds__(256) void router_kernel(
    const float* __restrict__ x,     // [T][D] fp32
    const float* __restrict__ rwp,   // [E][D] fp32
    const float* __restrict__ biasp, // [E]    fp32
    unsigned short* __restrict__ xb, // [T][D] bf16 out
    int* __restrict__ cnt, int* __restrict__ tlist,
    int* __restrict__ pos, float* __restrict__ pw)
{
    const int t    = blockIdx.x * 4 + (threadIdx.x >> 6);
    const int lane = threadIdx.x & 63;
    const float* xr = x + (size_t)t * DIMV + lane * 16;
    float xf[16];
#pragma unroll
    for (int q = 0; q < 4; q++) {
        float4 v = *(const float4*)(xr + q * 4);
        xf[q*4+0] = v.x; xf[q*4+1] = v.y; xf[q*4+2] = v.z; xf[q*4+3] = v.w;
    }
    {
        u16x8 o0, o1;
#pragma unroll
        for (int j = 0; j < 8; j++) { o0[j] = f2bf(xf[j]); o1[j] = f2bf(xf[8 + j]); }
        unsigned short* xo = xb + (size_t)t * DIMV + lane * 16;
        *(u16x8*)xo = o0;
        *(u16x8*)(xo + 8) = o1;
    }
    float acc[NE];
#pragma unroll
    for (int e = 0; e < NE; e++) {
        const float* wr = rwp + (size_t)e * DIMV + lane * 16;
        float s = 0.f;
#pragma unroll
        for (int q = 0; q < 4; q++) {
            float4 v = *(const float4*)(wr + q * 4);
            s += xf[q*4+0]*v.x + xf[q*4+1]*v.y + xf[q*4+2]*v.z + xf[q*4+3]*v.w;
        }
        acc[e] = s;
    }
#pragma unroll
    for (int e = 0; e < NE; e++)
#pragma unroll
        for (int off = 32; off; off >>= 1) acc[e] += __shfl_xor(acc[e], off, 64);

    if (lane == 0) {
        float lg[NE];
#pragma unroll
        for (int e = 0; e < NE; e++) lg[e] = acc[e] + biasp[e];
        int e0 = 0;
#pragma unroll
        for (int e = 1; e < NE; e++) if (lg[e] > lg[e0]) e0 = e;
        int e1 = (e0 == 0) ? 1 : 0;
#pragma unroll
        for (int e = 0; e < NE; e++) if (e != e0 && lg[e] > lg[e1]) e1 = e;
        float z  = __expf(lg[e1] - lg[e0]);
        float p0 = 1.f / (1.f + z);
        float p1 = z  / (1.f + z);
        int s0 = atomicAdd(cnt + e0, 1);
        tlist[e0 * CAP + s0] = t;
        int s1 = atomicAdd(cnt + e1, 1);
        tlist[e1 * CAP + s1] = t;
        pos[2 * t + 0] = e0 * CAP + s0;
        pos[2 * t + 1] = e1 * CAP + s1;
        pw[2 * t + 0] = p0;
        pw[2 * t + 1] = p1;
    }
}

// ---------------------------------------------------------------- cvt+transpose
// fp32 [R][C] tile -> bf16 [C][R]; optional w1/w3 interleave remap of the
// output row: h -> 32*(h>>4) + 16*ubit + (h&15)  (16-col groups of g|u).
template<int R, int C>
__device__ __forceinline__ void ctrans_body(
    const float* __restrict__ src, unsigned short* __restrict__ dstp,
    unsigned short (*tile)[66], int ileave, int ubit)
{
    const int c0 = blockIdx.x * 64, r0 = blockIdx.y * 64;
    const int tid = threadIdx.x;
    const int lr = tid >> 4;            // 0..15
    const int lc = (tid & 15) * 4;      // 0,4,..,60
#pragma unroll
    for (int i = 0; i < 4; i++) {
        int r = lr + 16 * i;
        float4 v = *(const float4*)(src + (size_t)(r0 + r) * C + (c0 + lc));
        ushort4 o; o.x = f2bf(v.x); o.y = f2bf(v.y); o.z = f2bf(v.z); o.w = f2bf(v.w);
        *(ushort4*)&tile[r][lc] = o;
    }
    __syncthreads();
    const int oc  = tid >> 3;           // 0..31
    const int orr = (tid & 7) * 8;      // 0..56
#pragma unroll
    for (int i = 0; i < 2; i++) {
        int c = oc + 32 * i;
        int h = c0 + c;
        int row = ileave ? (((h >> 4) << 5) + ubit * 16 + (h & 15)) : h;
        u16x8 tmp;
#pragma unroll
        for (int j = 0; j < 8; j++) tmp[j] = tile[orr + j][c];
        *(u16x8*)(dstp + (size_t)row * R + (r0 + orr)) = tmp;
    }
}

// z: 0..7 w1[e]->wcat(u=0), 8..15 w3[e]->wcat(u=1), 16 sw1->scat, 17 sw3->scat
// z: 18..25 w2[e]->w2t, 26 sw2->sw2t   (no interleave)
__global__ __launch_bounds__(256) void ctrans_all(
    const float* __restrict__ w1, const float* __restrict__ w3,
    const float* __restrict__ sw1, const float* __restrict__ sw3,
    const float* __restrict__ w2, const float* __restrict__ sw2,
    unsigned short* __restrict__ wcat, unsigned short* __restrict__ scat,
    unsigned short* __restrict__ w2t, unsigned short* __restrict__ sw2t)
{
    __shared__ unsigned short tile[64][66];
    const int z = blockIdx.z;
    if (z < 18) {
        if (blockIdx.y >= DIMV / 64) return;
        const float* src; unsigned short* dstp; int u;
        if (z < 8)        { src = w1 + (size_t)z * DIMV * HIDV;       dstp = wcat + (size_t)z * NCAT * DIMV;       u = 0; }
        else if (z < 16)  { src = w3 + (size_t)(z - 8) * DIMV * HIDV; dstp = wcat + (size_t)(z - 8) * NCAT * DIMV; u = 1; }
        else if (z == 16) { src = sw1; dstp = scat; u = 0; }
        else              { src = sw3; dstp = scat; u = 1; }
        ctrans_body<DIMV, HIDV>(src, dstp, tile, 1, u);
    } else {
        if (blockIdx.x >= DIMV / 64) return;
        const float* src; unsigned short* dstp;
        if (z < 26) { src = w2 + (size_t)(z - 18) * HIDV * DIMV; dstp = w2t + (size_t)(z - 18) * DIMV * HIDV; }
        else        { src = sw2; dstp = sw2t; }
        ctrans_body<HIDV, DIMV>(src, dstp, tile, 0, 0);
    }
}

// ================================================================
// 8-phase 256x256 BK=64 GEMM (T2 swizzle + T3/T4 counted vmcnt + T5 setprio)
// 512 thr = 8 waves (2M x 4N), per-wave 128x64 (acc[8][4]).
// LDS 128 KiB: A,B each [2 buf][2 kk-slab][256 rows][64 B]; kk-slabs make
// half-tile consumption staggered: last LDS read of Bk0=P1, Ak0=P2, Bk1=P3,
// Ak1=P4.  Issue schedule (1 half/phase): P1:Ak1(t+1) P2:Bk0(t+2) P3:Ak0(t+2)
// P4:Bk1(t+2) -- each half X(t+2) issued exactly one phase after X(t)'s last
// read (write-after-read safe behind that phase's barrier).  One counted
// s_waitcnt vmcnt(6) per K-tile at P4 retires exactly tile t+1's 4 halves
// (14 loads in flight max, 6 = 3 newest halves allowed outstanding);
// boundary tiles (t >= NT-2) drain with vmcnt(0).  Raw s_barrier only --
// never __syncthreads (its vmcnt(0) drain is the m97 35%-MfmaUtil ceiling).
// Swizzle: chunk c of each 64B row lives at c ^ (row&3); staged via linear
// LDS dest + inverse-swizzled per-lane GLOBAL source (both-sides rule).
// ================================================================

// ---------------------------------------------------------------- up GEMM
// N=4096 interleaved (g,u) columns; SwiGLU fused epilogue -> hbuf bf16.
__global__ __launch_bounds__(512, 2) void up_gemm8(
    const unsigned short* __restrict__ x,     // [T][D] bf16
    const unsigned short* __restrict__ wcat,  // [E][4096][D] bf16 interleaved
    const unsigned short* __restrict__ scat,  // [4096][D]
    const int* __restrict__ cnt, const int* __restrict__ tlist,
    unsigned short* __restrict__ hbuf)        // [ASSIGN_TOT][H] bf16
{
    const int g = blockIdx.z;
    int n_rows, row_off = 0;
    const unsigned short* Bp;
    if (g < NE) {
        for (int e = 0; e < g; e++) row_off += cnt[e];
        n_rows = cnt[g];
        Bp = wcat + (size_t)g * NCAT * DIMV;
    } else { n_rows = T_TOK; row_off = ROUTED; Bp = scat; }
    const int m0 = blockIdx.y * 256;
    if (m0 >= n_rows) return;
    const int n0 = blockIdx.x * 256;

    extern __shared__ __align__(16) unsigned short smem[];
    unsigned short* As = smem;           // [2][2][256][32] shorts (64 KB)
    unsigned short* Bs = smem + 32768;   // same (64 KB)

    const int tid  = threadIdx.x;
    const int lane = tid & 63;
    const int wave = tid >> 6;
    const int wm = wave >> 2, wn = wave & 3;
    const int m16 = lane & 15, quad = lane >> 4;

    // staging: each gll16 call = 512 thr * 16B = 8KB = 128 rows * 64B slab-rows
    const int sr = tid >> 2;                        // row 0..127 in call
    const int sc = (((tid & 3) ^ (sr & 3)) << 3);   // inverse-swizzled src chunk

    int tA0, tA1;
    if (g < NE) {
        int ra = m0 + sr;       if (ra >= n_rows) ra = n_rows - 1;
        int rb = m0 + 128 + sr; if (rb >= n_rows) rb = n_rows - 1;
        tA0 = tlist[g * CAP + ra];
        tA1 = tlist[g * CAP + rb];
    } else { tA0 = m0 + sr; tA1 = m0 + 128 + sr; }
    const unsigned short* sA0 = x + (size_t)tA0 * DIMV + sc;
    const unsigned short* sA1 = x + (size_t)tA1 * DIMV + sc;
    const unsigned short* sB0 = Bp + (size_t)(n0 + sr) * DIMV + sc;
    const unsigned short* sB1 = Bp + (size_t)(n0 + 128 + sr) * DIMV + sc;

    unsigned short* dA = As + wave * 512;    // wave-uniform base (HW adds lane*16)
    unsigned short* dB = Bs + wave * 512;

#define UPSA(t, kk) { unsigned short* d_ = dA + (((t) & 1) << 14) + ((kk) << 13); \
        gll16(sA0 + (t) * 64 + (kk) * 32, d_); gll16(sA1 + (t) * 64 + (kk) * 32, d_ + 4096); }
#define UPSB(t, kk) { unsigned short* d_ = dB + (((t) & 1) << 14) + ((kk) << 13); \
        gll16(sB0 + (t) * 64 + (kk) * 32, d_); gll16(sB1 + (t) * 64 + (kk) * 32, d_ + 4096); }

    // frag read bases (swizzled chunk = quad ^ (row&3) = quad ^ (m16&3))
    const unsigned short* Afb = As + (wm * 128 + m16) * 32 + ((quad ^ (m16 & 3)) << 3);
    const unsigned short* Bfb = Bs + (wn * 64  + m16) * 32 + ((quad ^ (m16 & 3)) << 3);

    // prologue: issue order Bk0(0) Ak0(0) Bk1(0) Ak1(0) Bk0(1) Ak0(1) Bk1(1);
    // vmcnt(6) retires tile 0's 4 halves (8 oldest loads of 14)
    UPSB(0, 0); UPSA(0, 0); UPSB(0, 1); UPSA(0, 1);
    UPSB(1, 0); UPSA(1, 0); UPSB(1, 1);
    asm volatile("s_waitcnt vmcnt(6)" ::: "memory");
    __builtin_amdgcn_s_barrier();

    floatx4 acc[8][4] = {};
    bf16x8 af[4], bfr[4];

#define NTU 16
    for (int t = 0; t < NTU; ++t) {
        const int pb = (t & 1) << 14;
        const unsigned short* Ab = Afb + pb;
        const unsigned short* Bb = Bfb + pb;
        // ---- P1: read A(kk0,mi0-3)+B(kk0,nj0-3); issue Ak1(t+1)
#pragma unroll
        for (int i = 0; i < 4; i++) af[i]  = *(const bf16x8*)(Ab + i * 512);
#pragma unroll
        for (int j = 0; j < 4; j++) bfr[j] = *(const bf16x8*)(Bb + j * 512);
        if (t + 1 < NTU) UPSA(t + 1, 1);
        __builtin_amdgcn_s_barrier();
        asm volatile("s_waitcnt lgkmcnt(0)" ::: "memory");
        __builtin_amdgcn_s_setprio(1);
#pragma unroll
        for (int i = 0; i < 4; i++)
#pragma unroll
            for (int j = 0; j < 4; j++)
                acc[i][j] = __builtin_amdgcn_mfma_f32_16x16x32_bf16(af[i], bfr[j], acc[i][j], 0, 0, 0);
        __builtin_amdgcn_s_setprio(0);
        __builtin_amdgcn_s_barrier();
        // ---- P2: read A(kk0,mi4-7); issue Bk0(t+2)
#pragma unroll
        for (int i = 0; i < 4; i++) af[i] = *(const bf16x8*)(Ab + (4 + i) * 512);
        if (t + 2 < NTU) UPSB(t + 2, 0);
        __builtin_amdgcn_s_barrier();
        asm volatile("s_waitcnt lgkmcnt(0)" ::: "memory");
        __builtin_amdgcn_s_setprio(1);
#pragma unroll
        for (int i = 0; i < 4; i++)
#pragma unroll
            for (int j = 0; j < 4; j++)
                acc[4 + i][j] = __builtin_amdgcn_mfma_f32_16x16x32_bf16(af[i], bfr[j], acc[4 + i][j], 0, 0, 0);
        __builtin_amdgcn_s_setprio(0);
        __builtin_amdgcn_s_barrier();
        // ---- P3: read A(kk1,mi0-3)+B(kk1,nj0-3); issue Ak0(t+2)
#pragma unroll
        for (int i = 0; i < 4; i++) af[i]  = *(const bf16x8*)(Ab + 8192 + i * 512);
#pragma unroll
        for (int j = 0; j < 4; j++) bfr[j] = *(const bf16x8*)(Bb + 8192 + j * 512);
        if (t + 2 < NTU) UPSA(t + 2, 0);
        __builtin_amdgcn_s_barrier();
        asm volatile("s_waitcnt lgkmcnt(0)" ::: "memory");
        __builtin_amdgcn_s_setprio(1);
#pragma unroll
        for (int i = 0; i < 4; i++)
#pragma unroll
            for (int j = 0; j < 4; j++)
                acc[i][j] = __builtin_amdgcn_mfma_f32_16x16x32_bf16(af[i], bfr[j], acc[i][j], 0, 0, 0);
        __builtin_amdgcn_s_setprio(0);
        __builtin_amdgcn_s_barrier();
        // ---- P4: read A(kk1,mi4-7); issue Bk1(t+2); counted vmcnt once/tile
#pragma unroll
        for (int i = 0; i < 4; i++) af[i] = *(const bf16x8*)(Ab + 8192 + (4 + i) * 512);
        if (t + 2 < NTU) UPSB(t + 2, 1);
        __builtin_amdgcn_s_barrier();
        asm volatile("s_waitcnt lgkmcnt(0)" ::: "memory");
        __builtin_amdgcn_s_setprio(1);
#pragma unroll
        for (int i = 0; i < 4; i++)
#pragma unroll
            for (int j = 0; j < 4; j++)
                acc[4 + i][j] = __builtin_amdgcn_mfma_f32_16x16x32_bf16(af[i], bfr[j], acc[4 + i][j], 0, 0, 0);
        __builtin_amdgcn_s_setprio(0);
        if (t < NTU - 2) { asm volatile("s_waitcnt vmcnt(6)" ::: "memory"); }
        else             { asm volatile("s_waitcnt vmcnt(0)" ::: "memory"); }
        __builtin_amdgcn_s_barrier();
    }
#undef NTU
#undef UPSA
#undef UPSB

    // epilogue: nj pairs (0,1)/(2,3) = (g,u) for same h (interleaved wcat)
    const int hb = (n0 >> 1) + wn * 32;
#pragma unroll
    for (int mi = 0; mi < 8; mi++) {
#pragma unroll
        for (int ii = 0; ii < 4; ii++) {
            int r = m0 + wm * 128 + mi * 16 + quad * 4 + ii;
            if (r < n_rows) {
                unsigned short* hr = hbuf + (size_t)(row_off + r) * HIDV;
#pragma unroll
                for (int p = 0; p < 2; p++) {
                    float gv = acc[mi][2 * p][ii], uv = acc[mi][2 * p + 1][ii];
                    float s  = gv / (1.0f + __expf(-gv));
                    hr[hb + p * 16 + m16] = f2bf(s * uv);
                }
            }
        }
    }
}

// ---------------------------------------------------------------- down GEMM
// same 8-phase structure; A rows contiguous (no gather); N=1024, K=2048.
__global__ __launch_bounds__(512, 2) void down_gemm8(
    const unsigned short* __restrict__ hbuf,  // [ASSIGN_TOT][H] bf16
    const unsigned short* __restrict__ w2t,   // [E][D][H] bf16 n-major
    const unsigned short* __restrict__ sw2t,  // [D][H]
    const int* __restrict__ cnt,
    unsigned short* __restrict__ dbuf)        // [ASSIGN_TOT][D] bf16
{
    const int g = blockIdx.z;
    int n_rows, row_off = 0;
    const unsigned short* Bp;
    if (g < NE) {
        for (int e = 0; e < g; e++) row_off += cnt[e];
        n_rows = cnt[g];
        Bp = w2t + (size_t)g * DIMV * HIDV;
    } else { n_rows = T_TOK; row_off = ROUTED; Bp = sw2t; }
    const int m0 = blockIdx.y * 256;
    if (m0 >= n_rows) return;
    const int n0 = blockIdx.x * 256;

    extern __shared__ __align__(16) unsigned short smem[];
    unsigned short* As = smem;
    unsigned short* Bs = smem + 32768;

    const int tid  = threadIdx.x;
    const int lane = tid & 63;
    const int wave = tid >> 6;
    const int wm = wave >> 2, wn = wave & 3;
    const int m16 = lane & 15, quad = lane >> 4;

    const int sr = tid >> 2;
    const int sc = (((tid & 3) ^ (sr & 3)) << 3);

    const unsigned short* sA0 = hbuf + (size_t)(row_off + m0 + sr) * HIDV + sc;
    const unsigned short* sA1 = sA0 + (size_t)128 * HIDV;
    const unsigned short* sB0 = Bp + (size_t)(n0 + sr) * HIDV + sc;
    const unsigned short* sB1 = sB0 + (size_t)128 * HIDV;

    unsigned short* dA = As + wave * 512;
    unsigned short* dB = Bs + wave * 512;

#define DNSA(t, kk) { unsigned short* d_ = dA + (((t) & 1) << 14) + ((kk) << 13); \
        gll16(sA0 + (t) * 64 + (kk) * 32, d_); gll16(sA1 + (t) * 64 + (kk) * 32, d_ + 4096); }
#define DNSB(t, kk) { unsigned short* d_ = dB + (((t) & 1) << 14) + ((kk) << 13); \
        gll16(sB0 + (t) * 64 + (kk) * 32, d_); gll16(sB1 + (t) * 64 + (kk) * 32, d_ + 4096); }

    const unsigned short* Afb = As + (wm * 128 + m16) * 32 + ((quad ^ (m16 & 3)) << 3);
    const unsigned short* Bfb = Bs + (wn * 64  + m16) * 32 + ((quad ^ (m16 & 3)) << 3);

    DNSB(0, 0); DNSA(0, 0); DNSB(0, 1); DNSA(0, 1);
    DNSB(1, 0); DNSA(1, 0); DNSB(1, 1);
    asm volatile("s_waitcnt vmcnt(6)" ::: "memory");
    __builtin_amdgcn_s_barrier();

    floatx4 acc[8][4] = {};
    bf16x8 af[4], bfr[4];

#define NTD 32
    for (int t = 0; t < NTD; ++t) {
        const int pb = (t & 1) << 14;
        const unsigned short* Ab = Afb + pb;
        const unsigned short* Bb = Bfb + pb;
        // ---- P1
#pragma unroll
        for (int i = 0; i < 4; i++) af[i]  = *(const bf16x8*)(Ab + i * 512);
#pragma unroll
        for (int j = 0; j < 4; j++) bfr[j] = *(const bf16x8*)(Bb + j * 512);
        if (t + 1 < NTD) DNSA(t + 1, 1);
        __builtin_amdgcn_s_barrier();
        asm volatile("s_waitcnt lgkmcnt(0)" ::: "memory");
        __builtin_amdgcn_s_setprio(1);
#pragma unroll
        for (int i = 0; i < 4; i++)
#pragma unroll
            for (int j = 0; j < 4; j++)
                acc[i][j] = __builtin_amdgcn_mfma_f32_16x16x32_bf16(af[i], bfr[j], acc[i][j], 0, 0, 0);
        __builtin_amdgcn_s_setprio(0);
        __builtin_amdgcn_s_barrier();
        // ---- P2
#pragma unroll
        for (int i = 0; i < 4; i++) af[i] = *(const bf16x8*)(Ab + (4 + i) * 512);
        if (t + 2 < NTD) DNSB(t + 2, 0);
        __builtin_amdgcn_s_barrier();
        asm volatile("s_waitcnt lgkmcnt(0)" ::: "memory");
        __builtin_amdgcn_s_setprio(1);
#pragma unroll
        for (int i = 0; i < 4; i++)
#pragma unroll
            for (int j = 0; j < 4; j++)
                acc[4 + i][j] = __builtin_amdgcn_mfma_f32_16x16x32_bf16(af[i], bfr[j], acc[4 + i][j], 0, 0, 0);
        __builtin_amdgcn_s_setprio(0);
        __builtin_amdgcn_s_barrier();
        // ---- P3
#pragma unroll
        for (int i = 0; i < 4; i++) af[i]  = *(const bf16x8*)(Ab + 8192 + i * 512);
#pragma unroll
        for (int j = 0; j < 4; j++) bfr[j] = *(const bf16x8*)(Bb + 8192 + j * 512);
        if (t + 2 < NTD) DNSA(t + 2, 0);
        __builtin_amdgcn_s_barrier();
        asm volatile("s_waitcnt lgkmcnt(0)" ::: "memory");
        __builtin_amdgcn_s_setprio(1);
#pragma unroll
        for (int i = 0; i < 4; i++)
#pragma unroll
            for (int j = 0; j < 4; j++)
                acc[i][j] = __builtin_amdgcn_mfma_f32_16x16x32_bf16(af[i], bfr[j], acc[i][j], 0, 0, 0);
        __builtin_amdgcn_s_setprio(0);
        __builtin_amdgcn_s_barrier();
        // ---- P4
#pragma unroll
        for (int i = 0; i < 4; i++) af[i] = *(const bf16x8*)(Ab + 8192 + (4 + i) * 512);
        if (t + 2 < NTD) DNSB(t + 2, 1);
        __builtin_amdgcn_s_barrier();
        asm volatile("s_waitcnt lgkmcnt(0)" ::: "memory");
        __builtin_amdgcn_s_setprio(1);
#pragma unroll
        for (int i = 0; i < 4; i++)
#pragma unroll
            for (int j = 0; j < 4; j++)
                acc[4 + i][j] = __builtin_amdgcn_mfma_f32_16x16x32_bf16(af[i], bfr[j], acc[4 + i][j], 0, 0, 0);
        __builtin_amdgcn_s_setprio(0);
        if (t < NTD - 2) { asm volatile("s_waitcnt vmcnt(6)" ::: "memory"); }
        else             { asm volatile("s_waitcnt vmcnt(0)" ::: "memory"); }
        __builtin_amdgcn_s_barrier();
    }
#undef NTD
#undef DNSA
#undef DNSB

#pragma unroll
    for (int mi = 0; mi < 8; mi++) {
#pragma unroll
        for (int ii = 0; ii < 4; ii++) {
            int r = m0 + wm * 128 + mi * 16 + quad * 4 + ii;
            if (r < n_rows) {
                unsigned short* drow = dbuf + (size_t)(row_off + r) * DIMV;
#pragma unroll
                for (int nj = 0; nj < 4; nj++)
                    drow[n0 + wn * 64 + nj * 16 + m16] = f2bf(acc[mi][nj][ii]);
            }
        }
    }
}

// ---------------------------------------------------------------- combine
__global__ __launch_bounds__(256) void combine_kernel(
    const unsigned short* __restrict__ dbuf,
    const int* __restrict__ cnt, const int* __restrict__ pos,
    const float* __restrict__ pw, float* __restrict__ outp)
{
    const int tid = threadIdx.x;
    const int t = blockIdx.x * 2 + (tid >> 7);
    const int c = (tid & 127) * 8;
    int goff[NE];
    {
        int s = 0;
#pragma unroll
        for (int e = 0; e < NE; e++) { goff[e] = s; s += cnt[e]; }
    }
    const int p0 = pos[2 * t], p1 = pos[2 * t + 1];
    const float w0 = pw[2 * t], w1 = pw[2 * t + 1];
    const int r0 = goff[p0 >> 13] + (p0 & (CAP - 1));
    const int r1 = goff[p1 >> 13] + (p1 & (CAP - 1));
    const u16x8 v0 = *(const u16x8*)(dbuf + (size_t)r0 * DIMV + c);
    const u16x8 v1 = *(const u16x8*)(dbuf + (size_t)r1 * DIMV + c);
    const u16x8 vs = *(const u16x8*)(dbuf + (size_t)(ROUTED + t) * DIMV + c);
    float o[8];
#pragma unroll
    for (int j = 0; j < 8; j++)
        o[j] = w0 * bf2f(v0[j]) + w1 * bf2f(v1[j]) + bf2f(vs[j]);
    float* op = outp + (size_t)t * DIMV + c;
    *(float4*)op       = make_float4(o[0], o[1], o[2], o[3]);
    *(float4*)(op + 4) = make_float4(o[4], o[5], o[6], o[7]);
}

// ---------------------------------------------------------------- launch
extern "C" void kernel_launch(void* const* d_in, const int* in_sizes, int n_in,
                              void* d_out, int out_size, void* d_ws, size_t ws_size,
                              hipStream_t stream)
{
    (void)in_sizes; (void)n_in; (void)out_size; (void)ws_size;
    const float* x    = (const float*)d_in[0];   // [T][D] fp32
    const float* rw   = (const float*)d_in[1];   // [E][D]
    const float* bias = (const float*)d_in[2];   // [E]
    const float* w1   = (const float*)d_in[3];   // [E][D][H]
    const float* w3   = (const float*)d_in[4];
    const float* w2   = (const float*)d_in[5];   // [E][H][D]
    const float* sw1  = (const float*)d_in[6];   // [1][D][H]
    const float* sw3  = (const float*)d_in[7];
    const float* sw2  = (const float*)d_in[8];   // [1][H][D]
    float* outp = (float*)d_out;                 // [T][D] fp32

    char* p = (char*)d_ws;
    auto alloc = [&](size_t b) { char* r = p; p += (b + 255) & ~(size_t)255; return r; };
    int*   cnt   = (int*)  alloc(64);
    int*   tlist = (int*)  alloc((size_t)NE * CAP * 4);
    int*   pos   = (int*)  alloc((size_t)T_TOK * 2 * 4);
    float* pw    = (float*)alloc((size_t)T_TOK * 2 * 4);
    unsigned short* xb   = (unsigned short*)alloc((size_t)T_TOK * DIMV * 2);
    unsigned short* hbuf = (unsigned short*)alloc((size_t)ASSIGN_TOT * HIDV * 2);
    unsigned short* wcat = (unsigned short*)alloc((size_t)NE * NCAT * DIMV * 2);  // 64 MB
    unsigned short* scat = (unsigned short*)alloc((size_t)NCAT * DIMV * 2);       // 8 MB
    unsigned short* w2t  = (unsigned short*)alloc((size_t)NE * DIMV * HIDV * 2);  // 32 MB
    unsigned short* sw2t = (unsigned short*)alloc((size_t)DIMV * HIDV * 2);       // 4 MB
    // dbuf (48 MB) aliases wcat (64 MB): dead after up_gemm8, before down_gemm8
    unsigned short* dbuf = wcat;

    hipMemsetAsync(cnt, 0, 64, stream);

    dim3 blk(256);
    router_kernel<<<dim3(T_TOK/4), blk, 0, stream>>>(x, rw, bias, xb, cnt, tlist, pos, pw);
    ctrans_all<<<dim3(HIDV/64, HIDV/64, 27), blk, 0, stream>>>(w1, w3, sw1, sw3, w2, sw2,
                                                               wcat, scat, w2t, sw2t);
    up_gemm8<<<dim3(NCAT/256, 32, 9), dim3(512), 131072, stream>>>(xb, wcat, scat,
                                                                   cnt, tlist, hbuf);
    down_gemm8<<<dim3(DIMV/256, 32, 9), dim3(512), 131072, stream>>>(hbuf, w2t, sw2t,
                                                                     cnt, dbuf);
    combine_kernel<<<dim3(T_TOK/2), blk, 0, stream>>>(dbuf, cnt, pos, pw, outp);
}

// Round 2
// 789.886 us; speedup vs baseline: 1.0866x; 1.0379x over previous
//
#include <hip/hip_runtime.h>
#include <stdint.h>

// Problem constants (B*L=8192 tokens, D=1024, H=2048, E=8 top-2, S=1 shared)
#define T_TOK 8192
#define DIMV  1024
#define HIDV  2048
#define NE    8
#define CAP   8192          // per-expert token list capacity (2^13)
#define ROUTED 16384        // total routed assignments
#define ASSIGN_TOT 24576    // routed + 8192 shared rows
#define NCAT  4096          // interleaved up-proj N: w1|w3 in 16-col groups

typedef __attribute__((ext_vector_type(8))) short          bf16x8;
typedef __attribute__((ext_vector_type(8))) unsigned short u16x8;
typedef __attribute__((ext_vector_type(4))) float          floatx4;

__device__ __forceinline__ unsigned short f2bf(float f) {
    union { float f; unsigned int i; } v; v.f = f;
    unsigned int i = v.i;
    return (unsigned short)((i + 0x7FFFu + ((i >> 16) & 1u)) >> 16);   // RNE
}
__device__ __forceinline__ float bf2f(unsigned short u) {
    union { unsigned int i; float f; } v; v.i = ((unsigned int)u) << 16; return v.f;
}

// async global->LDS, 16B/lane; lds base wave-uniform (HW adds lane*16)
__device__ __forceinline__ void gll16(const void* g, void* l) {
    __builtin_amdgcn_global_load_lds((const __attribute__((address_space(1))) void*)g,
                                     (__attribute__((address_space(3))) void*)l,
                                     16, 0, 0);
}

// ---------------------------------------------------------------- router
// one wave per token: fp32 logits, top-2 (lowest-index tie-break), softmax.
__global__ __launch_bounds__(256) void router_kernel(
    const float* __restrict__ x,     // [T][D] fp32
    const float* __restrict__ rwp,   // [E][D] fp32
    const float* __restrict__ biasp, // [E]    fp32
    unsigned short* __restrict__ xb, // [T][D] bf16 out
    int* __restrict__ cnt, int* __restrict__ tlist,
    int* __restrict__ pos, float* __restrict__ pw)
{
    const int t    = blockIdx.x * 4 + (threadIdx.x >> 6);
    const int lane = threadIdx.x & 63;
    const float* xr = x + (size_t)t * DIMV + lane * 16;
    float xf[16];
#pragma unroll
    for (int q = 0; q < 4; q++) {
        float4 v = *(const float4*)(xr + q * 4);
        xf[q*4+0] = v.x; xf[q*4+1] = v.y; xf[q*4+2] = v.z; xf[q*4+3] = v.w;
    }
    {
        u16x8 o0, o1;
#pragma unroll
        for (int j = 0; j < 8; j++) { o0[j] = f2bf(xf[j]); o1[j] = f2bf(xf[8 + j]); }
        unsigned short* xo = xb + (size_t)t * DIMV + lane * 16;
        *(u16x8*)xo = o0;
        *(u16x8*)(xo + 8) = o1;
    }
    float acc[NE];
#pragma unroll
    for (int e = 0; e < NE; e++) {
        const float* wr = rwp + (size_t)e * DIMV + lane * 16;
        float s = 0.f;
#pragma unroll
        for (int q = 0; q < 4; q++) {
            float4 v = *(const float4*)(wr + q * 4);
            s += xf[q*4+0]*v.x + xf[q*4+1]*v.y + xf[q*4+2]*v.z + xf[q*4+3]*v.w;
        }
        acc[e] = s;
    }
#pragma unroll
    for (int e = 0; e < NE; e++)
#pragma unroll
        for (int off = 32; off; off >>= 1) acc[e] += __shfl_xor(acc[e], off, 64);

    if (lane == 0) {
        float lg[NE];
#pragma unroll
        for (int e = 0; e < NE; e++) lg[e] = acc[e] + biasp[e];
        int e0 = 0;
#pragma unroll
        for (int e = 1; e < NE; e++) if (lg[e] > lg[e0]) e0 = e;
        int e1 = (e0 == 0) ? 1 : 0;
#pragma unroll
        for (int e = 0; e < NE; e++) if (e != e0 && lg[e] > lg[e1]) e1 = e;
        float z  = __expf(lg[e1] - lg[e0]);
        float p0 = 1.f / (1.f + z);
        float p1 = z  / (1.f + z);
        int s0 = atomicAdd(cnt + e0, 1);
        tlist[e0 * CAP + s0] = t;
        int s1 = atomicAdd(cnt + e1, 1);
        tlist[e1 * CAP + s1] = t;
        pos[2 * t + 0] = e0 * CAP + s0;
        pos[2 * t + 1] = e1 * CAP + s1;
        pw[2 * t + 0] = p0;
        pw[2 * t + 1] = p1;
    }
}

// ---------------------------------------------------------------- cvt+transpose
// fp32 [R][C] tile -> bf16 [C][R]; optional w1/w3 interleave remap of the
// output row: h -> 32*(h>>4) + 16*ubit + (h&15)  (16-col groups of g|u).
template<int R, int C>
__device__ __forceinline__ void ctrans_body(
    const float* __restrict__ src, unsigned short* __restrict__ dstp,
    unsigned short (*tile)[66], int ileave, int ubit)
{
    const int c0 = blockIdx.x * 64, r0 = blockIdx.y * 64;
    const int tid = threadIdx.x;
    const int lr = tid >> 4;            // 0..15
    const int lc = (tid & 15) * 4;      // 0,4,..,60
#pragma unroll
    for (int i = 0; i < 4; i++) {
        int r = lr + 16 * i;
        float4 v = *(const float4*)(src + (size_t)(r0 + r) * C + (c0 + lc));
        ushort4 o; o.x = f2bf(v.x); o.y = f2bf(v.y); o.z = f2bf(v.z); o.w = f2bf(v.w);
        *(ushort4*)&tile[r][lc] = o;
    }
    __syncthreads();
    const int oc  = tid >> 3;           // 0..31
    const int orr = (tid & 7) * 8;      // 0..56
#pragma unroll
    for (int i = 0; i < 2; i++) {
        int c = oc + 32 * i;
        int h = c0 + c;
        int row = ileave ? (((h >> 4) << 5) + ubit * 16 + (h & 15)) : h;
        u16x8 tmp;
#pragma unroll
        for (int j = 0; j < 8; j++) tmp[j] = tile[orr + j][c];
        *(u16x8*)(dstp + (size_t)row * R + (r0 + orr)) = tmp;
    }
}

// z: 0..7 w1[e]->wcat(u=0), 8..15 w3[e]->wcat(u=1), 16 sw1->scat, 17 sw3->scat
// z: 18..25 w2[e]->w2t, 26 sw2->sw2t   (no interleave)
__global__ __launch_bounds__(256) void ctrans_all(
    const float* __restrict__ w1, const float* __restrict__ w3,
    const float* __restrict__ sw1, const float* __restrict__ sw3,
    const float* __restrict__ w2, const float* __restrict__ sw2,
    unsigned short* __restrict__ wcat, unsigned short* __restrict__ scat,
    unsigned short* __restrict__ w2t, unsigned short* __restrict__ sw2t)
{
    __shared__ unsigned short tile[64][66];
    const int z = blockIdx.z;
    if (z < 18) {
        if (blockIdx.y >= DIMV / 64) return;
        const float* src; unsigned short* dstp; int u;
        if (z < 8)        { src = w1 + (size_t)z * DIMV * HIDV;       dstp = wcat + (size_t)z * NCAT * DIMV;       u = 0; }
        else if (z < 16)  { src = w3 + (size_t)(z - 8) * DIMV * HIDV; dstp = wcat + (size_t)(z - 8) * NCAT * DIMV; u = 1; }
        else if (z == 16) { src = sw1; dstp = scat; u = 0; }
        else              { src = sw3; dstp = scat; u = 1; }
        ctrans_body<DIMV, HIDV>(src, dstp, tile, 1, u);
    } else {
        if (blockIdx.x >= DIMV / 64) return;
        const float* src; unsigned short* dstp;
        if (z < 26) { src = w2 + (size_t)(z - 18) * HIDV * DIMV; dstp = w2t + (size_t)(z - 18) * DIMV * HIDV; }
        else        { src = sw2; dstp = sw2t; }
        ctrans_body<HIDV, DIMV>(src, dstp, tile, 0, 0);
    }
}

// ================================================================
// 8-phase 256x256 BK=64 GEMM (T2 swizzle + T3/T4 counted vmcnt + T5 setprio)
// 512 thr = 8 waves (2M x 4N), per-wave 128x64 (acc[8][4]).
// LDS 128 KiB: A,B each [2 buf][2 kk-slab][256 rows][64 B].
// Bank-conflict swizzle (64B rows): byte addr = row*64 + chunk*16, so
// bank-group = (row&1)*16 + chunk*4 -- row bit 0 enters via the stride.
// Swizzle must use row bits 1-2:  chunk ^= (row>>1)&3   (round-1 used
// row&3 -> bit0 redundant -> 8-way conflict, 1.97e7 cycles; this is the
// proven 0-conflict pattern from the m97-style kernel on identical rows).
// Staged via linear LDS dest + inverse-swizzled per-lane GLOBAL source.
// Issue schedule (1 half/phase): P1:Ak1(t+1) P2:Bk0(t+2) P3:Ak0(t+2)
// P4:Bk1(t+2); one counted s_waitcnt vmcnt(6) per K-tile at P4; boundary
// tiles drain vmcnt(0).  Raw s_barrier only -- never __syncthreads.
// ================================================================

// ---------------------------------------------------------------- up GEMM
// N=4096 interleaved (g,u) columns; SwiGLU fused epilogue -> hbuf bf16.
__global__ __launch_bounds__(512, 2) void up_gemm8(
    const unsigned short* __restrict__ x,     // [T][D] bf16
    const unsigned short* __restrict__ wcat,  // [E][4096][D] bf16 interleaved
    const unsigned short* __restrict__ scat,  // [4096][D]
    const int* __restrict__ cnt, const int* __restrict__ tlist,
    unsigned short* __restrict__ hbuf)        // [ASSIGN_TOT][H] bf16
{
    const int g = blockIdx.z;
    int n_rows, row_off = 0;
    const unsigned short* Bp;
    if (g < NE) {
        for (int e = 0; e < g; e++) row_off += cnt[e];
        n_rows = cnt[g];
        Bp = wcat + (size_t)g * NCAT * DIMV;
    } else { n_rows = T_TOK; row_off = ROUTED; Bp = scat; }
    const int m0 = blockIdx.y * 256;
    if (m0 >= n_rows) return;
    const int n0 = blockIdx.x * 256;

    extern __shared__ __align__(16) unsigned short smem[];
    unsigned short* As = smem;           // [2][2][256][32] shorts (64 KB)
    unsigned short* Bs = smem + 32768;   // same (64 KB)

    const int tid  = threadIdx.x;
    const int lane = tid & 63;
    const int wave = tid >> 6;
    const int wm = wave >> 2, wn = wave & 3;
    const int m16 = lane & 15, quad = lane >> 4;

    // staging: each gll16 call = 512 thr * 16B = 8KB = 128 rows * 64B slab-rows
    const int sr = tid >> 2;                               // row 0..127 in call
    const int sc = (((tid & 3) ^ ((sr >> 1) & 3)) << 3);   // inverse-swizzled src chunk

    int tA0, tA1;
    if (g < NE) {
        int ra = m0 + sr;       if (ra >= n_rows) ra = n_rows - 1;
        int rb = m0 + 128 + sr; if (rb >= n_rows) rb = n_rows - 1;
        tA0 = tlist[g * CAP + ra];
        tA1 = tlist[g * CAP + rb];
    } else { tA0 = m0 + sr; tA1 = m0 + 128 + sr; }
    const unsigned short* sA0 = x + (size_t)tA0 * DIMV + sc;
    const unsigned short* sA1 = x + (size_t)tA1 * DIMV + sc;
    const unsigned short* sB0 = Bp + (size_t)(n0 + sr) * DIMV + sc;
    const unsigned short* sB1 = Bp + (size_t)(n0 + 128 + sr) * DIMV + sc;

    unsigned short* dA = As + wave * 512;    // wave-uniform base (HW adds lane*16)
    unsigned short* dB = Bs + wave * 512;

#define UPSA(t, kk) { unsigned short* d_ = dA + (((t) & 1) << 14) + ((kk) << 13); \
        gll16(sA0 + (t) * 64 + (kk) * 32, d_); gll16(sA1 + (t) * 64 + (kk) * 32, d_ + 4096); }
#define UPSB(t, kk) { unsigned short* d_ = dB + (((t) & 1) << 14) + ((kk) << 13); \
        gll16(sB0 + (t) * 64 + (kk) * 32, d_); gll16(sB1 + (t) * 64 + (kk) * 32, d_ + 4096); }

    // frag read bases: swizzled chunk = quad ^ ((row>>1)&3) = quad ^ ((m16>>1)&3)
    const unsigned short* Afb = As + (wm * 128 + m16) * 32 + ((quad ^ ((m16 >> 1) & 3)) << 3);
    const unsigned short* Bfb = Bs + (wn * 64  + m16) * 32 + ((quad ^ ((m16 >> 1) & 3)) << 3);

    // prologue: issue order Bk0(0) Ak0(0) Bk1(0) Ak1(0) Bk0(1) Ak0(1) Bk1(1);
    // vmcnt(6) retires tile 0's 4 halves (8 oldest loads of 14)
    UPSB(0, 0); UPSA(0, 0); UPSB(0, 1); UPSA(0, 1);
    UPSB(1, 0); UPSA(1, 0); UPSB(1, 1);
    asm volatile("s_waitcnt vmcnt(6)" ::: "memory");
    __builtin_amdgcn_s_barrier();

    floatx4 acc[8][4] = {};
    bf16x8 af[4], bfr[4];

#define NTU 16
    for (int t = 0; t < NTU; ++t) {
        const int pb = (t & 1) << 14;
        const unsigned short* Ab = Afb + pb;
        const unsigned short* Bb = Bfb + pb;
        // ---- P1: read A(kk0,mi0-3)+B(kk0,nj0-3); issue Ak1(t+1)
#pragma unroll
        for (int i = 0; i < 4; i++) af[i]  = *(const bf16x8*)(Ab + i * 512);
#pragma unroll
        for (int j = 0; j < 4; j++) bfr[j] = *(const bf16x8*)(Bb + j * 512);
        if (t + 1 < NTU) UPSA(t + 1, 1);
        __builtin_amdgcn_s_barrier();
        asm volatile("s_waitcnt lgkmcnt(0)" ::: "memory");
        __builtin_amdgcn_s_setprio(1);
#pragma unroll
        for (int i = 0; i < 4; i++)
#pragma unroll
            for (int j = 0; j < 4; j++)
                acc[i][j] = __builtin_amdgcn_mfma_f32_16x16x32_bf16(af[i], bfr[j], acc[i][j], 0, 0, 0);
        __builtin_amdgcn_s_setprio(0);
        __builtin_amdgcn_s_barrier();
        // ---- P2: read A(kk0,mi4-7); issue Bk0(t+2)
#pragma unroll
        for (int i = 0; i < 4; i++) af[i] = *(const bf16x8*)(Ab + (4 + i) * 512);
        if (t + 2 < NTU) UPSB(t + 2, 0);
        __builtin_amdgcn_s_barrier();
        asm volatile("s_waitcnt lgkmcnt(0)" ::: "memory");
        __builtin_amdgcn_s_setprio(1);
#pragma unroll
        for (int i = 0; i < 4; i++)
#pragma unroll
            for (int j = 0; j < 4; j++)
                acc[4 + i][j] = __builtin_amdgcn_mfma_f32_16x16x32_bf16(af[i], bfr[j], acc[4 + i][j], 0, 0, 0);
        __builtin_amdgcn_s_setprio(0);
        __builtin_amdgcn_s_barrier();
        // ---- P3: read A(kk1,mi0-3)+B(kk1,nj0-3); issue Ak0(t+2)
#pragma unroll
        for (int i = 0; i < 4; i++) af[i]  = *(const bf16x8*)(Ab + 8192 + i * 512);
#pragma unroll
        for (int j = 0; j < 4; j++) bfr[j] = *(const bf16x8*)(Bb + 8192 + j * 512);
        if (t + 2 < NTU) UPSA(t + 2, 0);
        __builtin_amdgcn_s_barrier();
        asm volatile("s_waitcnt lgkmcnt(0)" ::: "memory");
        __builtin_amdgcn_s_setprio(1);
#pragma unroll
        for (int i = 0; i < 4; i++)
#pragma unroll
            for (int j = 0; j < 4; j++)
                acc[i][j] = __builtin_amdgcn_mfma_f32_16x16x32_bf16(af[i], bfr[j], acc[i][j], 0, 0, 0);
        __builtin_amdgcn_s_setprio(0);
        __builtin_amdgcn_s_barrier();
        // ---- P4: read A(kk1,mi4-7); issue Bk1(t+2); counted vmcnt once/tile
#pragma unroll
        for (int i = 0; i < 4; i++) af[i] = *(const bf16x8*)(Ab + 8192 + (4 + i) * 512);
        if (t + 2 < NTU) UPSB(t + 2, 1);
        __builtin_amdgcn_s_barrier();
        asm volatile("s_waitcnt lgkmcnt(0)" ::: "memory");
        __builtin_amdgcn_s_setprio(1);
#pragma unroll
        for (int i = 0; i < 4; i++)
#pragma unroll
            for (int j = 0; j < 4; j++)
                acc[4 + i][j] = __builtin_amdgcn_mfma_f32_16x16x32_bf16(af[i], bfr[j], acc[4 + i][j], 0, 0, 0);
        __builtin_amdgcn_s_setprio(0);
        if (t < NTU - 2) { asm volatile("s_waitcnt vmcnt(6)" ::: "memory"); }
        else             { asm volatile("s_waitcnt vmcnt(0)" ::: "memory"); }
        __builtin_amdgcn_s_barrier();
    }
#undef NTU
#undef UPSA
#undef UPSB

    // epilogue: nj pairs (0,1)/(2,3) = (g,u) for same h (interleaved wcat)
    const int hb = (n0 >> 1) + wn * 32;
#pragma unroll
    for (int mi = 0; mi < 8; mi++) {
#pragma unroll
        for (int ii = 0; ii < 4; ii++) {
            int r = m0 + wm * 128 + mi * 16 + quad * 4 + ii;
            if (r < n_rows) {
                unsigned short* hr = hbuf + (size_t)(row_off + r) * HIDV;
#pragma unroll
                for (int p = 0; p < 2; p++) {
                    float gv = acc[mi][2 * p][ii], uv = acc[mi][2 * p + 1][ii];
                    float s  = gv / (1.0f + __expf(-gv));
                    hr[hb + p * 16 + m16] = f2bf(s * uv);
                }
            }
        }
    }
}

// ---------------------------------------------------------------- down GEMM
// same 8-phase structure; A rows contiguous (no gather); N=1024, K=2048.
__global__ __launch_bounds__(512, 2) void down_gemm8(
    const unsigned short* __restrict__ hbuf,  // [ASSIGN_TOT][H] bf16
    const unsigned short* __restrict__ w2t,   // [E][D][H] bf16 n-major
    const unsigned short* __restrict__ sw2t,  // [D][H]
    const int* __restrict__ cnt,
    unsigned short* __restrict__ dbuf)        // [ASSIGN_TOT][D] bf16
{
    const int g = blockIdx.z;
    int n_rows, row_off = 0;
    const unsigned short* Bp;
    if (g < NE) {
        for (int e = 0; e < g; e++) row_off += cnt[e];
        n_rows = cnt[g];
        Bp = w2t + (size_t)g * DIMV * HIDV;
    } else { n_rows = T_TOK; row_off = ROUTED; Bp = sw2t; }
    const int m0 = blockIdx.y * 256;
    if (m0 >= n_rows) return;
    const int n0 = blockIdx.x * 256;

    extern __shared__ __align__(16) unsigned short smem[];
    unsigned short* As = smem;
    unsigned short* Bs = smem + 32768;

    const int tid  = threadIdx.x;
    const int lane = tid & 63;
    const int wave = tid >> 6;
    const int wm = wave >> 2, wn = wave & 3;
    const int m16 = lane & 15, quad = lane >> 4;

    const int sr = tid >> 2;
    const int sc = (((tid & 3) ^ ((sr >> 1) & 3)) << 3);

    const unsigned short* sA0 = hbuf + (size_t)(row_off + m0 + sr) * HIDV + sc;
    const unsigned short* sA1 = sA0 + (size_t)128 * HIDV;
    const unsigned short* sB0 = Bp + (size_t)(n0 + sr) * HIDV + sc;
    const unsigned short* sB1 = sB0 + (size_t)128 * HIDV;

    unsigned short* dA = As + wave * 512;
    unsigned short* dB = Bs + wave * 512;

#define DNSA(t, kk) { unsigned short* d_ = dA + (((t) & 1) << 14) + ((kk) << 13); \
        gll16(sA0 + (t) * 64 + (kk) * 32, d_); gll16(sA1 + (t) * 64 + (kk) * 32, d_ + 4096); }
#define DNSB(t, kk) { unsigned short* d_ = dB + (((t) & 1) << 14) + ((kk) << 13); \
        gll16(sB0 + (t) * 64 + (kk) * 32, d_); gll16(sB1 + (t) * 64 + (kk) * 32, d_ + 4096); }

    const unsigned short* Afb = As + (wm * 128 + m16) * 32 + ((quad ^ ((m16 >> 1) & 3)) << 3);
    const unsigned short* Bfb = Bs + (wn * 64  + m16) * 32 + ((quad ^ ((m16 >> 1) & 3)) << 3);

    DNSB(0, 0); DNSA(0, 0); DNSB(0, 1); DNSA(0, 1);
    DNSB(1, 0); DNSA(1, 0); DNSB(1, 1);
    asm volatile("s_waitcnt vmcnt(6)" ::: "memory");
    __builtin_amdgcn_s_barrier();

    floatx4 acc[8][4] = {};
    bf16x8 af[4], bfr[4];

#define NTD 32
    for (int t = 0; t < NTD; ++t) {
        const int pb = (t & 1) << 14;
        const unsigned short* Ab = Afb + pb;
        const unsigned short* Bb = Bfb + pb;
        // ---- P1
#pragma unroll
        for (int i = 0; i < 4; i++) af[i]  = *(const bf16x8*)(Ab + i * 512);
#pragma unroll
        for (int j = 0; j < 4; j++) bfr[j] = *(const bf16x8*)(Bb + j * 512);
        if (t + 1 < NTD) DNSA(t + 1, 1);
        __builtin_amdgcn_s_barrier();
        asm volatile("s_waitcnt lgkmcnt(0)" ::: "memory");
        __builtin_amdgcn_s_setprio(1);
#pragma unroll
        for (int i = 0; i < 4; i++)
#pragma unroll
            for (int j = 0; j < 4; j++)
                acc[i][j] = __builtin_amdgcn_mfma_f32_16x16x32_bf16(af[i], bfr[j], acc[i][j], 0, 0, 0);
        __builtin_amdgcn_s_setprio(0);
        __builtin_amdgcn_s_barrier();
        // ---- P2
#pragma unroll
        for (int i = 0; i < 4; i++) af[i] = *(const bf16x8*)(Ab + (4 + i) * 512);
        if (t + 2 < NTD) DNSB(t + 2, 0);
        __builtin_amdgcn_s_barrier();
        asm volatile("s_waitcnt lgkmcnt(0)" ::: "memory");
        __builtin_amdgcn_s_setprio(1);
#pragma unroll
        for (int i = 0; i < 4; i++)
#pragma unroll
            for (int j = 0; j < 4; j++)
                acc[4 + i][j] = __builtin_amdgcn_mfma_f32_16x16x32_bf16(af[i], bfr[j], acc[4 + i][j], 0, 0, 0);
        __builtin_amdgcn_s_setprio(0);
        __builtin_amdgcn_s_barrier();
        // ---- P3
#pragma unroll
        for (int i = 0; i < 4; i++) af[i]  = *(const bf16x8*)(Ab + 8192 + i * 512);
#pragma unroll
        for (int j = 0; j < 4; j++) bfr[j] = *(const bf16x8*)(Bb + 8192 + j * 512);
        if (t + 2 < NTD) DNSA(t + 2, 0);
        __builtin_amdgcn_s_barrier();
        asm volatile("s_waitcnt lgkmcnt(0)" ::: "memory");
        __builtin_amdgcn_s_setprio(1);
#pragma unroll
        for (int i = 0; i < 4; i++)
#pragma unroll
            for (int j = 0; j < 4; j++)
                acc[i][j] = __builtin_amdgcn_mfma_f32_16x16x32_bf16(af[i], bfr[j], acc[i][j], 0, 0, 0);
        __builtin_amdgcn_s_setprio(0);
        __builtin_amdgcn_s_barrier();
        // ---- P4
#pragma unroll
        for (int i = 0; i < 4; i++) af[i] = *(const bf16x8*)(Ab + 8192 + (4 + i) * 512);
        if (t + 2 < NTD) DNSB(t + 2, 1);
        __builtin_amdgcn_s_barrier();
        asm volatile("s_waitcnt lgkmcnt(0)" ::: "memory");
        __builtin_amdgcn_s_setprio(1);
#pragma unroll
        for (int i = 0; i < 4; i++)
#pragma unroll
            for (int j = 0; j < 4; j++)
                acc[4 + i][j] = __builtin_amdgcn_mfma_f32_16x16x32_bf16(af[i], bfr[j], acc[4 + i][j], 0, 0, 0);
        __builtin_amdgcn_s_setprio(0);
        if (t < NTD - 2) { asm volatile("s_waitcnt vmcnt(6)" ::: "memory"); }
        else             { asm volatile("s_waitcnt vmcnt(0)" ::: "memory"); }
        __builtin_amdgcn_s_barrier();
    }
#undef NTD
#undef DNSA
#undef DNSB

#pragma unroll
    for (int mi = 0; mi < 8; mi++) {
#pragma unroll
        for (int ii = 0; ii < 4; ii++) {
            int r = m0 + wm * 128 + mi * 16 + quad * 4 + ii;
            if (r < n_rows) {
                unsigned short* drow = dbuf + (size_t)(row_off + r) * DIMV;
#pragma unroll
                for (int nj = 0; nj < 4; nj++)
                    drow[n0 + wn * 64 + nj * 16 + m16] = f2bf(acc[mi][nj][ii]);
            }
        }
    }
}

// ---------------------------------------------------------------- combine
__global__ __launch_bounds__(256) void combine_kernel(
    const unsigned short* __restrict__ dbuf,
    const int* __restrict__ cnt, const int* __restrict__ pos,
    const float* __restrict__ pw, float* __restrict__ outp)
{
    const int tid = threadIdx.x;
    const int t = blockIdx.x * 2 + (tid >> 7);
    const int c = (tid & 127) * 8;
    int goff[NE];
    {
        int s = 0;
#pragma unroll
        for (int e = 0; e < NE; e++) { goff[e] = s; s += cnt[e]; }
    }
    const int p0 = pos[2 * t], p1 = pos[2 * t + 1];
    const float w0 = pw[2 * t], w1 = pw[2 * t + 1];
    const int r0 = goff[p0 >> 13] + (p0 & (CAP - 1));
    const int r1 = goff[p1 >> 13] + (p1 & (CAP - 1));
    const u16x8 v0 = *(const u16x8*)(dbuf + (size_t)r0 * DIMV + c);
    const u16x8 v1 = *(const u16x8*)(dbuf + (size_t)r1 * DIMV + c);
    const u16x8 vs = *(const u16x8*)(dbuf + (size_t)(ROUTED + t) * DIMV + c);
    float o[8];
#pragma unroll
    for (int j = 0; j < 8; j++)
        o[j] = w0 * bf2f(v0[j]) + w1 * bf2f(v1[j]) + bf2f(vs[j]);
    float* op = outp + (size_t)t * DIMV + c;
    *(float4*)op       = make_float4(o[0], o[1], o[2], o[3]);
    *(float4*)(op + 4) = make_float4(o[4], o[5], o[6], o[7]);
}

// ---------------------------------------------------------------- launch
extern "C" void kernel_launch(void* const* d_in, const int* in_sizes, int n_in,
                              void* d_out, int out_size, void* d_ws, size_t ws_size,
                              hipStream_t stream)
{
    (void)in_sizes; (void)n_in; (void)out_size; (void)ws_size;
    const float* x    = (const float*)d_in[0];   // [T][D] fp32
    const float* rw   = (const float*)d_in[1];   // [E][D]
    const float* bias = (const float*)d_in[2];   // [E]
    const float* w1   = (const float*)d_in[3];   // [E][D][H]
    const float* w3   = (const float*)d_in[4];
    const float* w2   = (const float*)d_in[5];   // [E][H][D]
    const float* sw1  = (const float*)d_in[6];   // [1][D][H]
    const float* sw3  = (const float*)d_in[7];
    const float* sw2  = (const float*)d_in[8];   // [1][H][D]
    float* outp = (float*)d_out;                 // [T][D] fp32

    char* p = (char*)d_ws;
    auto alloc = [&](size_t b) { char* r = p; p += (b + 255) & ~(size_t)255; return r; };
    int*   cnt   = (int*)  alloc(64);
    int*   tlist = (int*)  alloc((size_t)NE * CAP * 4);
    int*   pos   = (int*)  alloc((size_t)T_TOK * 2 * 4);
    float* pw    = (float*)alloc((size_t)T_TOK * 2 * 4);
    unsigned short* xb   = (unsigned short*)alloc((size_t)T_TOK * DIMV * 2);
    unsigned short* hbuf = (unsigned short*)alloc((size_t)ASSIGN_TOT * HIDV * 2);
    unsigned short* wcat = (unsigned short*)alloc((size_t)NE * NCAT * DIMV * 2);  // 64 MB
    unsigned short* scat = (unsigned short*)alloc((size_t)NCAT * DIMV * 2);       // 8 MB
    unsigned short* w2t  = (unsigned short*)alloc((size_t)NE * DIMV * HIDV * 2);  // 32 MB
    unsigned short* sw2t = (unsigned short*)alloc((size_t)DIMV * HIDV * 2);       // 4 MB
    // dbuf (48 MB) aliases wcat (64 MB): dead after up_gemm8, before down_gemm8
    unsigned short* dbuf = wcat;

    hipMemsetAsync(cnt, 0, 64, stream);

    dim3 blk(256);
    router_kernel<<<dim3(T_TOK/4), blk, 0, stream>>>(x, rw, bias, xb, cnt, tlist, pos, pw);
    ctrans_all<<<dim3(HIDV/64, HIDV/64, 27), blk, 0, stream>>>(w1, w3, sw1, sw3, w2, sw2,
                                                               wcat, scat, w2t, sw2t);
    up_gemm8<<<dim3(NCAT/256, 32, 9), dim3(512), 131072, stream>>>(xb, wcat, scat,
                                                                   cnt, tlist, hbuf);
    down_gemm8<<<dim3(DIMV/256, 32, 9), dim3(512), 131072, stream>>>(hbuf, w2t, sw2t,
                                                                     cnt, dbuf);
    combine_kernel<<<dim3(T_TOK/2), blk, 0, stream>>>(dbuf, cnt, pos, pw, outp);
}